// Round 8
// baseline (251.702 us; speedup 1.0000x reference)
//
#include <hip/hip_runtime.h>

#define N_NODES 10000
#define N_EDGES 160000
#define IN_DIM 128
#define HID 16
#define HEADS 50
#define OUT_DIM 10
#define N_GRAPHS 8
#define NHID (HEADS * HID) /* 800 */

// 8 head-groups: grp g owns heads [hstart(g), hstart(g+1)), 6 or 7 heads.
// hstart(g) = floor(g*50/8) -> 0,6,12,18,25,31,37,43,50
static __device__ __forceinline__ int hstart_of(int g) { return (g * 25) >> 2; }

typedef __attribute__((ext_vector_type(8))) short bfrag;   // 8 bf16 (4 VGPRs)
typedef __attribute__((ext_vector_type(4))) float ffrag;   // 4 fp32 acc

#define LOG2E 1.44269504088896340736f

// ---- bf16 helpers (self-contained, RNE) ----
static __device__ __forceinline__ unsigned short f2bf(float f) {
    union { float f; unsigned u; } v; v.f = f;
    unsigned u = v.u;
    unsigned r = (u + 0x7fffu + ((u >> 16) & 1u)) >> 16;
    return (unsigned short)r;
}
static __device__ __forceinline__ float bits2f(unsigned u) {
    union { unsigned u; float f; } v; v.u = u;
    return v.f;
}

// ---- K0: fused prep: xcast | wcast(transpose) | hsum zero ----
// blocks [0,1250): xbf = bf16(x)           (320000 float4s)
// blocks [1250,1650): wt[n][k] = bf16(W[k][n])  (102400 elems)
// blocks [1650,1807): hsum = 0             (40000 float4s)
__global__ __launch_bounds__(256) void prep_kernel(const float* __restrict__ x,
                                                   const float* __restrict__ W,
                                                   unsigned short* __restrict__ xbf,
                                                   unsigned short* __restrict__ wt,
                                                   float* __restrict__ hsum) {
    const int bid = blockIdx.x, tid = threadIdx.x;
    if (bid < 1250) {
        int t = bid * 256 + tid;  // exactly 320000
        float4 v = ((const float4*)x)[t];
        ushort4 o;
        o.x = f2bf(v.x); o.y = f2bf(v.y); o.z = f2bf(v.z); o.w = f2bf(v.w);
        ((ushort4*)xbf)[t] = o;
    } else if (bid < 1650) {
        int t = (bid - 1250) * 256 + tid;  // exactly 102400
        int n = t >> 7, k = t & 127;
        wt[t] = f2bf(W[k * NHID + n]);
    } else {
        int t = (bid - 1650) * 256 + tid;
        if (t < 40000) ((float4*)hsum)[t] = make_float4(0.f, 0.f, 0.f, 0.f);
    }
}

// ---- K1: MFMA bf16 GEMM, LDS-free, alpha fused (pre-scaled by log2e) ----
// grid (5, 79), block 256 = 4 waves. Wave: 32 rows x 160 cols = 2x10 tiles.
// Each 16-col tile == one head -> epilogue writes grp-packed xpg[g][n][8][16]
// and shfl-reduced ast/adt (already multiplied by log2e for exp2 in agg).
__global__ __launch_bounds__(256) void gemm_mfma(const unsigned short* __restrict__ xbf,
                                                 const unsigned short* __restrict__ wt,
                                                 const float* __restrict__ a_src,
                                                 const float* __restrict__ a_dst,
                                                 unsigned short* __restrict__ xpg,
                                                 float* __restrict__ astp,
                                                 float* __restrict__ adtp) {
    const int tid = threadIdx.x;
    const int wave = tid >> 6, lane = tid & 63;
    const int q = lane >> 4, r = lane & 15;
    const int m0 = blockIdx.y * 128 + wave * 32;
    const int h0 = blockIdx.x * 10;
    ffrag zf = {0.f, 0.f, 0.f, 0.f};
    ffrag acc[2][10];
#pragma unroll
    for (int mt = 0; mt < 2; mt++)
#pragma unroll
        for (int nt = 0; nt < 10; nt++) acc[mt][nt] = zf;

    // A reads may overrun past node 9999 (stores guarded); xbf is followed by
    // wt in the workspace so reads stay inside the allocation.
#pragma unroll
    for (int kc = 0; kc < IN_DIM; kc += 32) {
        bfrag a[2], b[10];
#pragma unroll
        for (int mt = 0; mt < 2; mt++)
            a[mt] = *(const bfrag*)(xbf + (m0 + mt * 16 + r) * IN_DIM + kc + q * 8);
#pragma unroll
        for (int nt = 0; nt < 10; nt++)
            b[nt] = *(const bfrag*)(wt + ((h0 + nt) * 16 + r) * IN_DIM + kc + q * 8);
#pragma unroll
        for (int mt = 0; mt < 2; mt++)
#pragma unroll
            for (int nt = 0; nt < 10; nt++)
                acc[mt][nt] = __builtin_amdgcn_mfma_f32_16x16x32_bf16(a[mt], b[nt],
                                                                      acc[mt][nt], 0, 0, 0);
    }
#pragma unroll
    for (int nt = 0; nt < 10; nt++) {
        const int h = h0 + nt;
        const int g = (8 * h + 7) / 50;
        const int hl = h - hstart_of(g);
        const float asw = a_src[h * HID + r] * LOG2E;
        const float adw = a_dst[h * HID + r] * LOG2E;
        unsigned short* xg = xpg + (size_t)g * (N_NODES * 128);
        float* ag = astp + g * (N_NODES * 8);
        float* dg = adtp + g * (N_NODES * 8);
#pragma unroll
        for (int mt = 0; mt < 2; mt++) {
            ffrag d = acc[mt][nt];  // rows m = m0+mt*16+q*4+i, col r
            float s[4], w[4];
#pragma unroll
            for (int i = 0; i < 4; i++) { s[i] = d[i] * asw; w[i] = d[i] * adw; }
#pragma unroll
            for (int off = 1; off < 16; off <<= 1) {
#pragma unroll
                for (int i = 0; i < 4; i++) {
                    s[i] += __shfl_xor(s[i], off);
                    w[i] += __shfl_xor(w[i], off);
                }
            }
#pragma unroll
            for (int i = 0; i < 4; i++) {
                const int node = m0 + mt * 16 + q * 4 + i;
                if (node < N_NODES) {
                    xg[node * 128 + hl * 16 + r] = f2bf(d[i]);
                    if (r == 0) {
                        ag[(node << 3) + hl] = s[i];
                        dg[(node << 3) + hl] = w[i];
                    }
                }
            }
        }
    }
}

// ---- K2: CSR build in ONE block: count + scan + deg-hist + degscatter ----
// LDS: cnt 40000 + scan 4096 + dh 256 + dcur 256 = 44.6 KB.
// offs has N_NODES+1 entries (deg = offs[n+1]-offs[n]); no global cnt.
__global__ __launch_bounds__(1024) void csr_build(const int* __restrict__ ei,
                                                  int* __restrict__ offs,
                                                  int* __restrict__ curs,
                                                  int* __restrict__ perm) {
    __shared__ int cnt_l[N_NODES];
    __shared__ int scan_l[1024];
    __shared__ int dh[64];
    __shared__ int dcur[64];
    const int t = threadIdx.x;
    for (int i = t; i < N_NODES; i += 1024) cnt_l[i] = 0;
    if (t < 64) dh[t] = 0;
    __syncthreads();
    for (int e = t; e < N_EDGES; e += 1024) atomicAdd(&cnt_l[ei[N_EDGES + e]], 1);
    __syncthreads();
    const int base = t * 10;
    int local[10];
    int s = 0;
#pragma unroll
    for (int i = 0; i < 10; i++) {
        int idx = base + i;
        int v = (idx < N_NODES) ? cnt_l[idx] : 0;
        if (idx < N_NODES) { int bb = v < 63 ? v : 63; atomicAdd(&dh[63 - bb], 1); }
        local[i] = s;
        s += v;
    }
    scan_l[t] = s;
    __syncthreads();
    for (int off = 1; off < 1024; off <<= 1) {
        int v = (t >= off) ? scan_l[t - off] : 0;
        __syncthreads();
        scan_l[t] += v;
        __syncthreads();
    }
    const int excl = scan_l[t] - s;
#pragma unroll
    for (int i = 0; i < 10; i++) {
        int idx = base + i;
        if (idx < N_NODES) {
            int o = excl + local[i];
            offs[idx] = o;
            curs[idx] = o;
        }
    }
    if (t == 1023) offs[N_NODES] = scan_l[1023];  // == N_EDGES
    __syncthreads();
    if (t == 0) {
        int a = 0;
#pragma unroll
        for (int b = 0; b < 64; b++) { int v = dh[b]; dcur[b] = a; a += v; }
    }
    __syncthreads();
    for (int n = t; n < N_NODES; n += 1024) {
        int d = cnt_l[n];
        d = d < 63 ? d : 63;
        int pos = atomicAdd(&dcur[63 - d], 1);  // descending degree
        perm[pos] = n;
    }
}

// ---- K3: edge scatter into dst-sorted ssrc ----
__global__ void scatter_kernel(const int* __restrict__ ei, int* __restrict__ curs,
                               int* __restrict__ ssrc) {
    int e = blockIdx.x * 256 + threadIdx.x;
    if (e < N_EDGES) {
        int d = ei[N_EDGES + e];
        int pos = atomicAdd(&curs[d], 1);
        ssrc[pos] = ei[e];
    }
}

// ---- K4: coalesced, barrier-free, scalar-addressed aggregation ----
// grid 20000 = 8 grps x 2500; blockIdx&7 -> grp (XCD round-robin; ~2.6MB slice
// L2-resident). Wave owns dst = perm[db*4+wave]. src wrapped in readfirstlane
// -> ast/xpg loads are saddr-form with loop-invariant voffsets (minimal VALU).
// Inactive pad lanes (hl >= cg) read 0xAA-poisoned pads (finite) and are
// masked via inv=0 before the cross-head reduce.
__global__ __launch_bounds__(256) void agg_kernel(const unsigned short* __restrict__ xpg,
                                                  const float* __restrict__ astp,
                                                  const float* __restrict__ adtp,
                                                  const int* __restrict__ offs,
                                                  const int* __restrict__ ssrc,
                                                  const int* __restrict__ perm,
                                                  float* __restrict__ hsum) {
    const int t = threadIdx.x;
    const int wave = t >> 6, lane = t & 63;
    const int g = blockIdx.x & 7;
    const int db = blockIdx.x >> 3;  // 0..2499
    const int cg = hstart_of(g + 1) - hstart_of(g);  // 6 or 7
    const int hl = lane >> 3;
    const int co = (hl << 4) + (lane & 7) * 2;  // element offset in 128-wide row
    const int dst = __builtin_amdgcn_readfirstlane(perm[db * 4 + wave]);
    const int start = __builtin_amdgcn_readfirstlane(offs[dst]);
    const int deg = __builtin_amdgcn_readfirstlane(offs[dst + 1]) - start;
    const float* ag = astp + g * (N_NODES * 8);
    const unsigned short* xg = xpg + (size_t)g * (N_NODES * 128);
    const float adv = adtp[g * (N_NODES * 8) + (dst << 3) + hl];
    float acc0 = 0.f, acc1 = 0.f, den = 0.f;
    int e = 0;
    for (; e + 1 < deg; e += 2) {
        const int s0 = __builtin_amdgcn_readfirstlane(ssrc[start + e]);
        const int s1 = __builtin_amdgcn_readfirstlane(ssrc[start + e + 1]);
        const float a0 = ag[(s0 << 3) + hl];
        const float a1 = ag[(s1 << 3) + hl];
        const unsigned p0 = *(const unsigned*)(xg + (s0 << 7) + co);
        const unsigned p1 = *(const unsigned*)(xg + (s1 << 7) + co);
        float l0 = a0 + adv; l0 = fmaxf(l0, 0.2f * l0);
        float l1 = a1 + adv; l1 = fmaxf(l1, 0.2f * l1);
        const float w0 = exp2f(l0), w1 = exp2f(l1);  // logits pre-scaled by log2e
        den += w0 + w1;
        acc0 = fmaf(w0, bits2f(p0 << 16), acc0);
        acc0 = fmaf(w1, bits2f(p1 << 16), acc0);
        acc1 = fmaf(w0, bits2f(p0 & 0xffff0000u), acc1);
        acc1 = fmaf(w1, bits2f(p1 & 0xffff0000u), acc1);
    }
    for (; e <= deg; e++) {  // tail + self loop
        const int s0 = __builtin_amdgcn_readfirstlane((e < deg) ? ssrc[start + e] : dst);
        const float a0 = ag[(s0 << 3) + hl];
        const unsigned p0 = *(const unsigned*)(xg + (s0 << 7) + co);
        float l0 = a0 + adv; l0 = fmaxf(l0, 0.2f * l0);
        const float w0 = exp2f(l0);
        den += w0;
        acc0 = fmaf(w0, bits2f(p0 << 16), acc0);
        acc1 = fmaf(w0, bits2f(p0 & 0xffff0000u), acc1);
    }
    const float inv = (hl < cg) ? (1.f / den) : 0.f;  // den>0: self loop
    float v0 = acc0 * inv, v1 = acc1 * inv;
    v0 += __shfl_xor(v0, 8);  v1 += __shfl_xor(v1, 8);
    v0 += __shfl_xor(v0, 16); v1 += __shfl_xor(v1, 16);
    v0 += __shfl_xor(v0, 32); v1 += __shfl_xor(v1, 32);
    if (lane < 8) {
        atomicAdd(&hsum[(dst << 4) + 2 * lane + 0], v0);
        atomicAdd(&hsum[(dst << 4) + 2 * lane + 1], v1);
    }
}

// ---- K5: per-graph mean pool (+ head mean + bias) + FC. One block per graph. ----
__global__ __launch_bounds__(256) void pool_kernel(const float* __restrict__ hsum,
                                                   const int* __restrict__ batch,
                                                   const float* __restrict__ bias,
                                                   const float* __restrict__ fc_w,
                                                   const float* __restrict__ fc_b,
                                                   float* __restrict__ out) {
    const int g = blockIdx.x;
    const int t = threadIdx.x;
    int a = 0, b = N_NODES;
    while (a < b) { int m = (a + b) >> 1; if (batch[m] < g) a = m + 1; else b = m; }
    const int lo = a;
    b = N_NODES;
    while (a < b) { int m = (a + b) >> 1; if (batch[m] < g + 1) a = m + 1; else b = m; }
    const int hi = a;
    const int cntn = hi - lo;
    float acc[16];
#pragma unroll
    for (int c = 0; c < 16; c++) acc[c] = 0.f;
    for (int n = lo + t; n < hi; n += 256) {
        const float4* r = (const float4*)(hsum + (n << 4));
        float4 v0 = r[0], v1 = r[1], v2 = r[2], v3 = r[3];
        acc[0] += v0.x; acc[1] += v0.y; acc[2] += v0.z; acc[3] += v0.w;
        acc[4] += v1.x; acc[5] += v1.y; acc[6] += v1.z; acc[7] += v1.w;
        acc[8] += v2.x; acc[9] += v2.y; acc[10] += v2.z; acc[11] += v2.w;
        acc[12] += v3.x; acc[13] += v3.y; acc[14] += v3.z; acc[15] += v3.w;
    }
    __shared__ float red[256][17];
#pragma unroll
    for (int c = 0; c < 16; c++) red[t][c] = acc[c];
    __syncthreads();
    for (int s = 128; s > 0; s >>= 1) {
        if (t < s)
#pragma unroll
            for (int c = 0; c < 16; c++) red[t][c] += red[t + s][c];
        __syncthreads();
    }
    __shared__ float pooled[16];
    if (t < 16) {
        float v = 0.f;
        if (cntn > 0) v = red[0][t] / ((float)cntn * (float)HEADS) + bias[t];
        pooled[t] = v;
    }
    __syncthreads();
    if (t < OUT_DIM) {
        float s = fc_b[t];
#pragma unroll
        for (int c = 0; c < HID; c++) s += pooled[c] * fc_w[c * OUT_DIM + t];
        out[g * OUT_DIM + t] = s;
    }
}

// ---- workspace layout (bytes) ----
#define XPG_OFF 0              /* 8*10000*8*16*2 = 20,480,000 */
#define ASTP_OFF 20480000      /* 8*10000*8*4    =  2,560,000 */
#define ADTP_OFF 23040000      /* 8*10000*8*4    =  2,560,000 */
#define XBF_OFF 25600000       /* 10000*128*2    =  2,560,000 (wt follows: OOB-read safe) */
#define WT_OFF 28160000        /* 800*128*2      =    204,800 */
#define SSRC_OFF 28364800      /* 160000*4       =    640,000 */
#define OFFS_OFF 29004800      /* 10001*4        =     40,004 (pad to 40064) */
#define CURS_OFF 29044864      /* 10000*4        =     40,000 */
#define PERM_OFF 29084864      /* 10000*4        =     40,000 */
#define HSUM_OFF 29124864      /* 10000*16*4     =    640,000 (zeroed in prep) */

extern "C" void kernel_launch(void* const* d_in, const int* in_sizes, int n_in,
                              void* d_out, int out_size, void* d_ws, size_t ws_size,
                              hipStream_t stream) {
    const float* x = (const float*)d_in[0];
    const int* ei = (const int*)d_in[1];
    const int* batch = (const int*)d_in[2];
    const float* W = (const float*)d_in[4];
    const float* a_src = (const float*)d_in[5];
    const float* a_dst = (const float*)d_in[6];
    const float* bias = (const float*)d_in[7];
    const float* fc_w = (const float*)d_in[8];
    const float* fc_b = (const float*)d_in[9];
    float* out = (float*)d_out;

    char* ws = (char*)d_ws;
    unsigned short* xpg = (unsigned short*)(ws + XPG_OFF);
    float* astp = (float*)(ws + ASTP_OFF);
    float* adtp = (float*)(ws + ADTP_OFF);
    unsigned short* xbf = (unsigned short*)(ws + XBF_OFF);
    unsigned short* wt = (unsigned short*)(ws + WT_OFF);
    int* ssrc = (int*)(ws + SSRC_OFF);
    int* offs = (int*)(ws + OFFS_OFF);
    int* curs = (int*)(ws + CURS_OFF);
    int* perm = (int*)(ws + PERM_OFF);
    float* hsum = (float*)(ws + HSUM_OFF);

    prep_kernel<<<1807, 256, 0, stream>>>(x, W, xbf, wt, hsum);
    gemm_mfma<<<dim3(5, (N_NODES + 127) / 128), 256, 0, stream>>>(
        xbf, wt, a_src, a_dst, xpg, astp, adtp);
    csr_build<<<1, 1024, 0, stream>>>(ei, offs, curs, perm);
    scatter_kernel<<<(N_EDGES + 255) / 256, 256, 0, stream>>>(ei, curs, ssrc);
    agg_kernel<<<8 * (N_NODES / 4), 256, 0, stream>>>(xpg, astp, adtp, offs, ssrc, perm, hsum);
    pool_kernel<<<N_GRAPHS, 256, 0, stream>>>(hsum, batch, bias, fc_w, fc_b, out);
}

// Round 9
// 228.587 us; speedup vs baseline: 1.1011x; 1.1011x over previous
//
#include <hip/hip_runtime.h>

#define N_NODES 10000
#define N_EDGES 160000
#define IN_DIM 128
#define HID 16
#define HEADS 50
#define OUT_DIM 10
#define N_GRAPHS 8
#define NHID (HEADS * HID) /* 800 */

// 8 head-groups: grp g owns heads [hstart(g), hstart(g+1)), 6 or 7 heads.
static __device__ __forceinline__ int hstart_of(int g) { return (g * 25) >> 2; }

typedef __attribute__((ext_vector_type(8))) short bfrag;   // 8 bf16 (4 VGPRs)
typedef __attribute__((ext_vector_type(4))) float ffrag;   // 4 fp32 acc

#define LOG2E 1.44269504088896340736f

// ---- bf16 helpers (self-contained, RNE) ----
static __device__ __forceinline__ unsigned short f2bf(float f) {
    union { float f; unsigned u; } v; v.f = f;
    unsigned u = v.u;
    unsigned r = (u + 0x7fffu + ((u >> 16) & 1u)) >> 16;
    return (unsigned short)r;
}
static __device__ __forceinline__ float bits2f(unsigned u) {
    union { unsigned u; float f; } v; v.u = u;
    return v.f;
}

// ---- K0: fused parallel prep: xcast | wcast(transpose) | hsum zero | edge count ----
// blocks [0,1250): xbf = bf16(x)                (320000 float4s)
// blocks [1250,1650): wt[n][k] = bf16(W[k][n])  (102400 elems)
// blocks [1650,1807): hsum = 0                  (40000 float4s)
// blocks [1807,2432): cnt[dst]++ per edge       (cnt zeroed by prior memset)
__global__ __launch_bounds__(256) void prep_kernel(const float* __restrict__ x,
                                                   const float* __restrict__ W,
                                                   const int* __restrict__ ei,
                                                   unsigned short* __restrict__ xbf,
                                                   unsigned short* __restrict__ wt,
                                                   float* __restrict__ hsum,
                                                   int* __restrict__ cnt) {
    const int bid = blockIdx.x, tid = threadIdx.x;
    if (bid < 1250) {
        int t = bid * 256 + tid;  // exactly 320000
        float4 v = ((const float4*)x)[t];
        ushort4 o;
        o.x = f2bf(v.x); o.y = f2bf(v.y); o.z = f2bf(v.z); o.w = f2bf(v.w);
        ((ushort4*)xbf)[t] = o;
    } else if (bid < 1650) {
        int t = (bid - 1250) * 256 + tid;  // exactly 102400
        int n = t >> 7, k = t & 127;
        wt[t] = f2bf(W[k * NHID + n]);
    } else if (bid < 1807) {
        int t = (bid - 1650) * 256 + tid;
        if (t < 40000) ((float4*)hsum)[t] = make_float4(0.f, 0.f, 0.f, 0.f);
    } else {
        int e = (bid - 1807) * 256 + tid;
        if (e < N_EDGES) atomicAdd(&cnt[ei[N_EDGES + e]], 1);
    }
}

// ---- K1: MFMA bf16 GEMM, LDS-free, alpha fused (pre-scaled by log2e) ----
// grid (10, 79), block 256 = 4 waves; wave: 32 rows x 80 cols = 2x5 tiles.
// 3160 waves -> ~3 waves/SIMD to hide global-load latency (no LDS staging).
__global__ __launch_bounds__(256) void gemm_mfma(const unsigned short* __restrict__ xbf,
                                                 const unsigned short* __restrict__ wt,
                                                 const float* __restrict__ a_src,
                                                 const float* __restrict__ a_dst,
                                                 unsigned short* __restrict__ xpg,
                                                 float* __restrict__ astp,
                                                 float* __restrict__ adtp) {
    const int tid = threadIdx.x;
    const int wave = tid >> 6, lane = tid & 63;
    const int q = lane >> 4, r = lane & 15;
    const int m0 = blockIdx.y * 128 + wave * 32;
    const int h0 = blockIdx.x * 5;
    ffrag zf = {0.f, 0.f, 0.f, 0.f};
    ffrag acc[2][5];
#pragma unroll
    for (int mt = 0; mt < 2; mt++)
#pragma unroll
        for (int nt = 0; nt < 5; nt++) acc[mt][nt] = zf;

    // A reads may overrun past node 9999 (stores guarded); xbf is followed by
    // wt in the workspace so reads stay inside the allocation.
#pragma unroll
    for (int kc = 0; kc < IN_DIM; kc += 32) {
        bfrag a[2], b[5];
#pragma unroll
        for (int mt = 0; mt < 2; mt++)
            a[mt] = *(const bfrag*)(xbf + (m0 + mt * 16 + r) * IN_DIM + kc + q * 8);
#pragma unroll
        for (int nt = 0; nt < 5; nt++)
            b[nt] = *(const bfrag*)(wt + ((h0 + nt) * 16 + r) * IN_DIM + kc + q * 8);
#pragma unroll
        for (int mt = 0; mt < 2; mt++)
#pragma unroll
            for (int nt = 0; nt < 5; nt++)
                acc[mt][nt] = __builtin_amdgcn_mfma_f32_16x16x32_bf16(a[mt], b[nt],
                                                                      acc[mt][nt], 0, 0, 0);
    }
#pragma unroll
    for (int nt = 0; nt < 5; nt++) {
        const int h = h0 + nt;
        const int g = (8 * h + 7) / 50;
        const int hl = h - hstart_of(g);
        const float asw = a_src[h * HID + r] * LOG2E;
        const float adw = a_dst[h * HID + r] * LOG2E;
        unsigned short* xg = xpg + (size_t)g * (N_NODES * 128);
        float* ag = astp + g * (N_NODES * 8);
        float* dg = adtp + g * (N_NODES * 8);
#pragma unroll
        for (int mt = 0; mt < 2; mt++) {
            ffrag d = acc[mt][nt];  // rows m = m0+mt*16+q*4+i, col r
            float s[4], w[4];
#pragma unroll
            for (int i = 0; i < 4; i++) { s[i] = d[i] * asw; w[i] = d[i] * adw; }
#pragma unroll
            for (int off = 1; off < 16; off <<= 1) {
#pragma unroll
                for (int i = 0; i < 4; i++) {
                    s[i] += __shfl_xor(s[i], off);
                    w[i] += __shfl_xor(w[i], off);
                }
            }
#pragma unroll
            for (int i = 0; i < 4; i++) {
                const int node = m0 + mt * 16 + q * 4 + i;
                if (node < N_NODES) {
                    xg[node * 128 + hl * 16 + r] = f2bf(d[i]);
                    if (r == 0) {
                        ag[(node << 3) + hl] = s[i];
                        dg[(node << 3) + hl] = w[i];
                    }
                }
            }
        }
    }
}

// ---- K2: scan (1 small block): cnt -> offs/curs, degree hist -> dcur ----
__global__ __launch_bounds__(1024) void scan_kernel(const int* __restrict__ cnt,
                                                    int* __restrict__ offs,
                                                    int* __restrict__ curs,
                                                    int* __restrict__ dcur) {
    __shared__ int lds[1024];
    __shared__ int dh[64];
    const int tid = threadIdx.x;
    if (tid < 64) dh[tid] = 0;
    __syncthreads();
    const int base = tid * 10;
    int local[10];
    int s = 0;
#pragma unroll
    for (int i = 0; i < 10; i++) {
        int idx = base + i;
        int v = (idx < N_NODES) ? cnt[idx] : 0;
        if (idx < N_NODES) { int bb = v < 63 ? v : 63; atomicAdd(&dh[63 - bb], 1); }
        local[i] = s;
        s += v;
    }
    lds[tid] = s;
    __syncthreads();
    for (int off = 1; off < 1024; off <<= 1) {
        int v = (tid >= off) ? lds[tid - off] : 0;
        __syncthreads();
        lds[tid] += v;
        __syncthreads();
    }
    const int excl = lds[tid] - s;
#pragma unroll
    for (int i = 0; i < 10; i++) {
        int idx = base + i;
        if (idx < N_NODES) {
            int o = excl + local[i];
            offs[idx] = o;
            curs[idx] = o;
        }
    }
    if (tid == 1023) offs[N_NODES] = lds[1023];  // == N_EDGES
    __syncthreads();
    if (tid == 0) {
        int a = 0;
#pragma unroll
        for (int b = 0; b < 64; b++) { int v = dh[b]; dcur[b] = a; a += v; }
    }
}

// ---- K3: fused parallel scatter: edge scatter | degree-sort scatter ----
// blocks [0,625): ssrc[curs[dst]++] = src ; blocks [625,665): perm by degree.
__global__ __launch_bounds__(256) void scatter_kernel(const int* __restrict__ ei,
                                                      int* __restrict__ curs,
                                                      int* __restrict__ ssrc,
                                                      const int* __restrict__ cnt,
                                                      int* __restrict__ dcur,
                                                      int* __restrict__ perm) {
    const int bid = blockIdx.x;
    if (bid < 625) {
        int e = bid * 256 + threadIdx.x;
        if (e < N_EDGES) {
            int d = ei[N_EDGES + e];
            int pos = atomicAdd(&curs[d], 1);
            ssrc[pos] = ei[e];
        }
    } else {
        int n = (bid - 625) * 256 + threadIdx.x;
        if (n < N_NODES) {
            int d = cnt[n];
            d = d < 63 ? d : 63;
            int pos = atomicAdd(&dcur[63 - d], 1);  // descending degree
            perm[pos] = n;
        }
    }
}

// ---- K4: coalesced, barrier-free, scalar-addressed aggregation ----
// grid 20000 = 8 grps x 2500; blockIdx&7 -> grp (XCD round-robin; ~2.6MB slice
// L2-resident). Wave owns dst = perm[db*4+wave]; src via readfirstlane ->
// saddr loads with loop-invariant voffsets. Pad lanes masked via inv=0.
__global__ __launch_bounds__(256) void agg_kernel(const unsigned short* __restrict__ xpg,
                                                  const float* __restrict__ astp,
                                                  const float* __restrict__ adtp,
                                                  const int* __restrict__ offs,
                                                  const int* __restrict__ ssrc,
                                                  const int* __restrict__ perm,
                                                  float* __restrict__ hsum) {
    const int t = threadIdx.x;
    const int wave = t >> 6, lane = t & 63;
    const int g = blockIdx.x & 7;
    const int db = blockIdx.x >> 3;  // 0..2499
    const int cg = hstart_of(g + 1) - hstart_of(g);  // 6 or 7
    const int hl = lane >> 3;
    const int co = (hl << 4) + (lane & 7) * 2;  // element offset in 128-wide row
    const int dst = __builtin_amdgcn_readfirstlane(perm[db * 4 + wave]);
    const int start = __builtin_amdgcn_readfirstlane(offs[dst]);
    const int deg = __builtin_amdgcn_readfirstlane(offs[dst + 1]) - start;
    const float* ag = astp + g * (N_NODES * 8);
    const unsigned short* xg = xpg + (size_t)g * (N_NODES * 128);
    const float adv = adtp[g * (N_NODES * 8) + (dst << 3) + hl];
    float acc0 = 0.f, acc1 = 0.f, den = 0.f;
    int e = 0;
    for (; e + 1 < deg; e += 2) {
        const int s0 = __builtin_amdgcn_readfirstlane(ssrc[start + e]);
        const int s1 = __builtin_amdgcn_readfirstlane(ssrc[start + e + 1]);
        const float a0 = ag[(s0 << 3) + hl];
        const float a1 = ag[(s1 << 3) + hl];
        const unsigned p0 = *(const unsigned*)(xg + (s0 << 7) + co);
        const unsigned p1 = *(const unsigned*)(xg + (s1 << 7) + co);
        float l0 = a0 + adv; l0 = fmaxf(l0, 0.2f * l0);
        float l1 = a1 + adv; l1 = fmaxf(l1, 0.2f * l1);
        const float w0 = exp2f(l0), w1 = exp2f(l1);  // logits pre-scaled by log2e
        den += w0 + w1;
        acc0 = fmaf(w0, bits2f(p0 << 16), acc0);
        acc0 = fmaf(w1, bits2f(p1 << 16), acc0);
        acc1 = fmaf(w0, bits2f(p0 & 0xffff0000u), acc1);
        acc1 = fmaf(w1, bits2f(p1 & 0xffff0000u), acc1);
    }
    for (; e <= deg; e++) {  // tail + self loop
        const int s0 = __builtin_amdgcn_readfirstlane((e < deg) ? ssrc[start + e] : dst);
        const float a0 = ag[(s0 << 3) + hl];
        const unsigned p0 = *(const unsigned*)(xg + (s0 << 7) + co);
        float l0 = a0 + adv; l0 = fmaxf(l0, 0.2f * l0);
        const float w0 = exp2f(l0);
        den += w0;
        acc0 = fmaf(w0, bits2f(p0 << 16), acc0);
        acc1 = fmaf(w0, bits2f(p0 & 0xffff0000u), acc1);
    }
    const float inv = (hl < cg) ? (1.f / den) : 0.f;  // den>0: self loop
    float v0 = acc0 * inv, v1 = acc1 * inv;
    v0 += __shfl_xor(v0, 8);  v1 += __shfl_xor(v1, 8);
    v0 += __shfl_xor(v0, 16); v1 += __shfl_xor(v1, 16);
    v0 += __shfl_xor(v0, 32); v1 += __shfl_xor(v1, 32);
    if (lane < 8) {
        atomicAdd(&hsum[(dst << 4) + 2 * lane + 0], v0);
        atomicAdd(&hsum[(dst << 4) + 2 * lane + 1], v1);
    }
}

// ---- K5: per-graph mean pool (+ head mean + bias) + FC. One block per graph. ----
__global__ __launch_bounds__(256) void pool_kernel(const float* __restrict__ hsum,
                                                   const int* __restrict__ batch,
                                                   const float* __restrict__ bias,
                                                   const float* __restrict__ fc_w,
                                                   const float* __restrict__ fc_b,
                                                   float* __restrict__ out) {
    const int g = blockIdx.x;
    const int t = threadIdx.x;
    int a = 0, b = N_NODES;
    while (a < b) { int m = (a + b) >> 1; if (batch[m] < g) a = m + 1; else b = m; }
    const int lo = a;
    b = N_NODES;
    while (a < b) { int m = (a + b) >> 1; if (batch[m] < g + 1) a = m + 1; else b = m; }
    const int hi = a;
    const int cntn = hi - lo;
    float acc[16];
#pragma unroll
    for (int c = 0; c < 16; c++) acc[c] = 0.f;
    for (int n = lo + t; n < hi; n += 256) {
        const float4* r = (const float4*)(hsum + (n << 4));
        float4 v0 = r[0], v1 = r[1], v2 = r[2], v3 = r[3];
        acc[0] += v0.x; acc[1] += v0.y; acc[2] += v0.z; acc[3] += v0.w;
        acc[4] += v1.x; acc[5] += v1.y; acc[6] += v1.z; acc[7] += v1.w;
        acc[8] += v2.x; acc[9] += v2.y; acc[10] += v2.z; acc[11] += v2.w;
        acc[12] += v3.x; acc[13] += v3.y; acc[14] += v3.z; acc[15] += v3.w;
    }
    __shared__ float red[256][17];
#pragma unroll
    for (int c = 0; c < 16; c++) red[t][c] = acc[c];
    __syncthreads();
    for (int s = 128; s > 0; s >>= 1) {
        if (t < s)
#pragma unroll
            for (int c = 0; c < 16; c++) red[t][c] += red[t + s][c];
        __syncthreads();
    }
    __shared__ float pooled[16];
    if (t < 16) {
        float v = 0.f;
        if (cntn > 0) v = red[0][t] / ((float)cntn * (float)HEADS) + bias[t];
        pooled[t] = v;
    }
    __syncthreads();
    if (t < OUT_DIM) {
        float s = fc_b[t];
#pragma unroll
        for (int c = 0; c < HID; c++) s += pooled[c] * fc_w[c * OUT_DIM + t];
        out[g * OUT_DIM + t] = s;
    }
}

// ---- workspace layout (bytes) ----
#define XPG_OFF 0              /* 8*10000*8*16*2 = 20,480,000 */
#define ASTP_OFF 20480000      /* 8*10000*8*4    =  2,560,000 */
#define ADTP_OFF 23040000      /* 8*10000*8*4    =  2,560,000 */
#define XBF_OFF 25600000       /* 10000*128*2    =  2,560,000 (wt follows: OOB-read safe) */
#define WT_OFF 28160000        /* 800*128*2      =    204,800 */
#define SSRC_OFF 28364800      /* 160000*4       =    640,000 */
#define OFFS_OFF 29004800      /* 10001*4        =     40,004 (pad to 40064) */
#define CURS_OFF 29044864      /* 10000*4        =     40,000 */
#define PERM_OFF 29084864      /* 10000*4        =     40,000 */
#define HSUM_OFF 29124864      /* 10000*16*4     =    640,000 (zeroed in prep) */
#define CNT_OFF 29764864       /* 10000*4        =     40,000 (zeroed by memset) */
#define DCUR_OFF 29804864      /* 64*4           =        256 */

extern "C" void kernel_launch(void* const* d_in, const int* in_sizes, int n_in,
                              void* d_out, int out_size, void* d_ws, size_t ws_size,
                              hipStream_t stream) {
    const float* x = (const float*)d_in[0];
    const int* ei = (const int*)d_in[1];
    const int* batch = (const int*)d_in[2];
    const float* W = (const float*)d_in[4];
    const float* a_src = (const float*)d_in[5];
    const float* a_dst = (const float*)d_in[6];
    const float* bias = (const float*)d_in[7];
    const float* fc_w = (const float*)d_in[8];
    const float* fc_b = (const float*)d_in[9];
    float* out = (float*)d_out;

    char* ws = (char*)d_ws;
    unsigned short* xpg = (unsigned short*)(ws + XPG_OFF);
    float* astp = (float*)(ws + ASTP_OFF);
    float* adtp = (float*)(ws + ADTP_OFF);
    unsigned short* xbf = (unsigned short*)(ws + XBF_OFF);
    unsigned short* wt = (unsigned short*)(ws + WT_OFF);
    int* ssrc = (int*)(ws + SSRC_OFF);
    int* offs = (int*)(ws + OFFS_OFF);
    int* curs = (int*)(ws + CURS_OFF);
    int* perm = (int*)(ws + PERM_OFF);
    float* hsum = (float*)(ws + HSUM_OFF);
    int* cntc = (int*)(ws + CNT_OFF);
    int* dcur = (int*)(ws + DCUR_OFF);

    hipMemsetAsync(ws + CNT_OFF, 0, 40000, stream);
    prep_kernel<<<2432, 256, 0, stream>>>(x, W, ei, xbf, wt, hsum, cntc);
    gemm_mfma<<<dim3(10, (N_NODES + 127) / 128), 256, 0, stream>>>(
        xbf, wt, a_src, a_dst, xpg, astp, adtp);
    scan_kernel<<<1, 1024, 0, stream>>>(cntc, offs, curs, dcur);
    scatter_kernel<<<665, 256, 0, stream>>>(ei, curs, ssrc, cntc, dcur, perm);
    agg_kernel<<<8 * (N_NODES / 4), 256, 0, stream>>>(xpg, astp, adtp, offs, ssrc, perm, hsum);
    pool_kernel<<<N_GRAPHS, 256, 0, stream>>>(hsum, batch, bias, fc_w, fc_b, out);
}